// Round 2
// baseline (95.289 us; speedup 1.0000x reference)
//
#include <hip/hip_runtime.h>
#include <hip/hip_bf16.h>
#include <cstddef>

// Hyperbolic supervised contrastive loss, fused.
// C=0.01, T=0.5, scale_by_T, artanh clamp 1-1e-5.
//
// Math notes:
//  - logits_max is always ~0 (diagonal dist=0) and cancels exactly in
//    log_probs = a_ij - log(sum_j' exp(a_ij')) -> skip the max pass.
//  - exp(logit) = ratio^20 with ratio = (|den|-r)/(|den|+r), r = sqrt(C*num_sq)
//    logit = -dist/T = 20*ln(ratio) = (20*ln2)*log2(ratio)
//  - per-row stats are additive over j -> atomicAdd partials, finalize after.

#define C_CONST 0.01f
#define TWO_C   0.02f
// ratio at nd = 1-1e-5:  (1e-5)/(2-1e-5)
#define RATIO_MIN 5.000025e-06f
#define LOGIT_SCALE 13.86294361119890619f   // 20*ln(2)
#define TEMP 0.5f

constexpr int BM = 64, BN = 64, DD = 128, LDP = 132;  // +4 pad: only free 2-way bank alias

__global__ void sq_kernel(const float* __restrict__ F, float* __restrict__ sq, int B) {
  int lane = threadIdx.x & 15;
  int row = blockIdx.x * 16 + (threadIdx.x >> 4);
  if (row >= B) return;
  const float4* fp = reinterpret_cast<const float4*>(F + (size_t)row * DD);
  float4 v1 = fp[lane * 2], v2 = fp[lane * 2 + 1];
  float s = v1.x * v1.x + v1.y * v1.y + v1.z * v1.z + v1.w * v1.w
          + v2.x * v2.x + v2.y * v2.y + v2.z * v2.z + v2.w * v2.w;
#pragma unroll
  for (int off = 1; off < 16; off <<= 1) s += __shfl_xor(s, off);
  if (lane == 0) sq[row] = s;
}

__global__ __launch_bounds__(256, 2) void
main_kernel(const float* __restrict__ F, const int* __restrict__ labels,
            const float* __restrict__ sq, float* __restrict__ denom,
            float* __restrict__ possum, float* __restrict__ npos,
            int B, int tilesPerSplit) {
  __shared__ float As[BM][LDP];
  __shared__ float Bs[BN][LDP];
  __shared__ int   labB[BN];
  __shared__ float sqB[BN];

  const int tid = threadIdx.x;
  const int tx = tid & 15;       // column group 0..15
  const int ty = tid >> 4;       // row group 0..15
  const int row0 = blockIdx.x * BM;

  // stage A tile (64 rows x 128 dims), coalesced float4
#pragma unroll
  for (int it = 0; it < 8; ++it) {
    int idx = tid + it * 256;
    int r = idx >> 5;
    int kq = (idx & 31) << 2;
    float4 v = *reinterpret_cast<const float4*>(&F[(size_t)(row0 + r) * DD + kq]);
    *reinterpret_cast<float4*>(&As[r][kq]) = v;
  }

  int rowi[4]; float si[4], pi[4]; int labR[4];
#pragma unroll
  for (int u = 0; u < 4; ++u) {
    rowi[u] = row0 + ty * 4 + u;
    si[u] = sq[rowi[u]];
    pi[u] = C_CONST * si[u];
    labR[u] = labels[rowi[u]];
  }

  float dacc[4] = {0.f, 0.f, 0.f, 0.f};
  float pacc[4] = {0.f, 0.f, 0.f, 0.f};
  float nacc[4] = {0.f, 0.f, 0.f, 0.f};

  for (int t = 0; t < tilesPerSplit; ++t) {
    const int col0 = (blockIdx.y * tilesPerSplit + t) * BN;
    __syncthreads();   // previous iteration's reads done before overwrite
#pragma unroll
    for (int it = 0; it < 8; ++it) {
      int idx = tid + it * 256;
      int c = idx >> 5;
      int kq = (idx & 31) << 2;
      float4 v = *reinterpret_cast<const float4*>(&F[(size_t)(col0 + c) * DD + kq]);
      *reinterpret_cast<float4*>(&Bs[c][kq]) = v;
    }
    if (tid < BN) {
      labB[tid] = labels[col0 + tid];
      sqB[tid]  = sq[col0 + tid];
    }
    __syncthreads();

    // 4x4 register tile dot products, K=128
    float acc[4][4] = {};
#pragma unroll
    for (int k = 0; k < DD; k += 4) {
      float4 av[4], bv[4];
#pragma unroll
      for (int u = 0; u < 4; ++u)
        av[u] = *reinterpret_cast<const float4*>(&As[ty * 4 + u][k]);
#pragma unroll
      for (int v = 0; v < 4; ++v)
        bv[v] = *reinterpret_cast<const float4*>(&Bs[tx + 16 * v][k]);
#pragma unroll
      for (int u = 0; u < 4; ++u)
#pragma unroll
        for (int v = 0; v < 4; ++v) {
          acc[u][v] = fmaf(av[u].x, bv[v].x, acc[u][v]);
          acc[u][v] = fmaf(av[u].y, bv[v].y, acc[u][v]);
          acc[u][v] = fmaf(av[u].z, bv[v].z, acc[u][v]);
          acc[u][v] = fmaf(av[u].w, bv[v].w, acc[u][v]);
        }
    }

    // epilogue: pair transform + accumulate row stats
#pragma unroll
    for (int vv = 0; vv < 4; ++vv) {
      const int col = col0 + tx + 16 * vv;
      const float sj = sqB[tx + 16 * vv];
      const float qv = C_CONST * sj;
      const int   lj = labB[tx + 16 * vv];
      const float b  = 1.f - qv;
#pragma unroll
      for (int u = 0; u < 4; ++u) {
        float g  = acc[u][vv];
        float tt = fmaf(-TWO_C, g, 1.f);            // 1 - 2Cg
        float a  = tt + pi[u];                      // 1 - 2Cg + C*si
        float den = fabsf(fmaf(pi[u], qv, tt));     // |1 - 2Cg + C^2 si sj|
        float ns = a * a * sj;                      // a^2 * x2(=sj)
        ns = fmaf(b * b, si[u], ns);                // + b^2 * y2(=si)
        ns = fmaf(-2.f * a * b, g, ns);             // + 2ab*xy (xy=-g)
        ns = fmaxf(ns, 0.f);
        float r = __builtin_amdgcn_sqrtf(C_CONST * ns);
        float ratio = (den - r) * __builtin_amdgcn_rcpf(den + r);
        ratio = fmaxf(ratio, RATIO_MIN);
        float P = __builtin_amdgcn_logf(ratio);     // log2(ratio); logit = 20*ln2*P
        float e = __builtin_amdgcn_exp2f(20.f * P); // exp(logit) = 2^(20P)
        bool diag = (col == rowi[u]);
        bool same = (lj == labR[u]) && !diag;
        dacc[u] += diag ? 0.f : e;
        pacc[u] += same ? LOGIT_SCALE * P : 0.f;
        nacc[u] += same ? 1.f : 0.f;
      }
    }
  }

  // reduce across the 16 tx lanes (contiguous within each wave)
#pragma unroll
  for (int u = 0; u < 4; ++u) {
    float d = dacc[u], p = pacc[u], n = nacc[u];
#pragma unroll
    for (int off = 1; off < 16; off <<= 1) {
      d += __shfl_xor(d, off);
      p += __shfl_xor(p, off);
      n += __shfl_xor(n, off);
    }
    if (tx == 0) {
      atomicAdd(&denom[rowi[u]], d);
      atomicAdd(&possum[rowi[u]], p);
      atomicAdd(&npos[rowi[u]], n);
    }
  }
}

__global__ void finalize_kernel(const float* __restrict__ denom,
                                const float* __restrict__ possum,
                                const float* __restrict__ npos,
                                float* __restrict__ out, int B) {
  float s_loss = 0.f, s_valid = 0.f;
  for (int i = threadIdx.x; i < B; i += 256) {
    float np = npos[i];
    if (np > 0.f) {
      float rl = -(possum[i] - np * logf(denom[i])) / np * TEMP;
      if (!(rl != rl)) s_loss += rl;   // NaN -> 0 like reference
      s_valid += 1.f;
    }
  }
#pragma unroll
  for (int off = 1; off < 64; off <<= 1) {
    s_loss += __shfl_xor(s_loss, off);
    s_valid += __shfl_xor(s_valid, off);
  }
  __shared__ float red[8];
  int wid = threadIdx.x >> 6;
  if ((threadIdx.x & 63) == 0) { red[wid] = s_loss; red[wid + 4] = s_valid; }
  __syncthreads();
  if (threadIdx.x == 0) {
    float L = red[0] + red[1] + red[2] + red[3];
    float V = red[4] + red[5] + red[6] + red[7];
    out[0] = L / fmaxf(V, 1.f);
  }
}

extern "C" void kernel_launch(void* const* d_in, const int* in_sizes, int n_in,
                              void* d_out, int out_size, void* d_ws, size_t ws_size,
                              hipStream_t stream) {
  const float* F = (const float*)d_in[0];
  const int* labels = (const int*)d_in[1];
  const int B = in_sizes[1];           // 4096

  float* sq     = (float*)d_ws;
  float* denom  = sq + B;
  float* possum = denom + B;
  float* npos   = possum + B;

  (void)hipMemsetAsync(d_ws, 0, sizeof(float) * 4 * (size_t)B, stream);
  sq_kernel<<<dim3((B + 15) / 16), dim3(256), 0, stream>>>(F, sq, B);

  const int gridY = 8;
  dim3 grid(B / BM, gridY);
  main_kernel<<<grid, dim3(256), 0, stream>>>(F, labels, sq, denom, possum, npos,
                                              B, (B / BN) / gridY);

  finalize_kernel<<<1, dim3(256), 0, stream>>>(denom, possum, npos, (float*)d_out, B);
}

// Round 3
// 74.221 us; speedup vs baseline: 1.2839x; 1.2839x over previous
//
#include <hip/hip_runtime.h>
#include <cstddef>

// Hyperbolic supervised contrastive loss, fused, MFMA split-bf16 Gram.
// G = F F^T with F = hi + lo (bf16 split): G ~= hi*hi^T + hi*lo^T + lo*hi^T.
// logits_max cancels (softmax shift invariance). Per-row stats additive -> atomics.
// exp(logit) = ratio^20, logit = 20*ln2*log2(ratio), ratio=(|den|-r)/(|den|+r).

typedef __bf16 bf16x8 __attribute__((ext_vector_type(8)));
typedef __bf16 bf16x4 __attribute__((ext_vector_type(4)));
typedef float  f32x4  __attribute__((ext_vector_type(4)));

#define C_CONST 0.01f
#define RATIO_MIN 5.000025e-06f          // ratio at clamp 1-1e-5
#define LOGIT_SCALE 13.86294361119890619f // 20*ln(2)
#define TEMP 0.5f
constexpr int DD = 128;

// bf16-split + row squared-norms + zero the stat arrays. 8 rows/block, 32 lanes/row.
__global__ __launch_bounds__(256) void prep_kernel(
    const float* __restrict__ F, __bf16* __restrict__ Fh, __bf16* __restrict__ Fl,
    float* __restrict__ sq, float* __restrict__ denom,
    float* __restrict__ possum, float* __restrict__ npos) {
  const int tid = threadIdx.x;
  const int lane = tid & 31;
  const int row = blockIdx.x * 8 + (tid >> 5);
  const float4 v = *reinterpret_cast<const float4*>(F + (size_t)row * DD + lane * 4);
  float s = v.x * v.x + v.y * v.y + v.z * v.z + v.w * v.w;
  bf16x4 h, lo;
  h[0] = (__bf16)v.x; lo[0] = (__bf16)(v.x - (float)h[0]);
  h[1] = (__bf16)v.y; lo[1] = (__bf16)(v.y - (float)h[1]);
  h[2] = (__bf16)v.z; lo[2] = (__bf16)(v.z - (float)h[2]);
  h[3] = (__bf16)v.w; lo[3] = (__bf16)(v.w - (float)h[3]);
  *reinterpret_cast<bf16x4*>(Fh + (size_t)row * DD + lane * 4) = h;
  *reinterpret_cast<bf16x4*>(Fl + (size_t)row * DD + lane * 4) = lo;
#pragma unroll
  for (int off = 1; off < 32; off <<= 1) s += __shfl_xor(s, off);
  if (lane == 0) { sq[row] = s; denom[row] = 0.f; possum[row] = 0.f; npos[row] = 0.f; }
}

// One 128x128 G tile per block. 4 waves; wave w owns 32 rows (2 row-frags x 8 col-frags).
// Fragments loaded straight from L2 (no LDS): lane ln=l&15 picks the row/col,
// lg=l>>4 picks the contiguous 16B k-slice; A and B use the SAME k-slot map so the
// MFMA-internal k permutation cancels.
__global__ __launch_bounds__(256) void gram_kernel(
    const __bf16* __restrict__ Fh, const __bf16* __restrict__ Fl,
    const float* __restrict__ sq, const int* __restrict__ labels,
    float* __restrict__ denom, float* __restrict__ possum, float* __restrict__ npos) {
  const int tid = threadIdx.x;
  const int l  = tid & 63;
  const int w  = tid >> 6;
  const int lg = l >> 4, ln = l & 15;
  const int row0 = blockIdx.x * 128 + w * 32;
  const int col0 = blockIdx.y * 128;

  f32x4 acc[2][8];
#pragma unroll
  for (int fi = 0; fi < 2; ++fi)
#pragma unroll
    for (int fj = 0; fj < 8; ++fj) acc[fi][fj] = (f32x4){0.f, 0.f, 0.f, 0.f};

  const __bf16* ArowH = Fh + (size_t)(row0 + ln) * DD + lg * 8;
  const __bf16* ArowL = Fl + (size_t)(row0 + ln) * DD + lg * 8;
  const __bf16* BrowH = Fh + (size_t)(col0 + ln) * DD + lg * 8;
  const __bf16* BrowL = Fl + (size_t)(col0 + ln) * DD + lg * 8;

#pragma unroll
  for (int kt = 0; kt < 4; ++kt) {
    bf16x8 ah[2], al[2];
#pragma unroll
    for (int fi = 0; fi < 2; ++fi) {
      ah[fi] = *reinterpret_cast<const bf16x8*>(ArowH + fi * 16 * DD + kt * 32);
      al[fi] = *reinterpret_cast<const bf16x8*>(ArowL + fi * 16 * DD + kt * 32);
    }
#pragma unroll
    for (int fj = 0; fj < 8; ++fj) {
      bf16x8 bh = *reinterpret_cast<const bf16x8*>(BrowH + fj * 16 * DD + kt * 32);
      bf16x8 bl = *reinterpret_cast<const bf16x8*>(BrowL + fj * 16 * DD + kt * 32);
#pragma unroll
      for (int fi = 0; fi < 2; ++fi) {
        acc[fi][fj] = __builtin_amdgcn_mfma_f32_16x16x32_bf16(ah[fi], bh, acc[fi][fj], 0, 0, 0);
        acc[fi][fj] = __builtin_amdgcn_mfma_f32_16x16x32_bf16(ah[fi], bl, acc[fi][fj], 0, 0, 0);
        acc[fi][fj] = __builtin_amdgcn_mfma_f32_16x16x32_bf16(al[fi], bh, acc[fi][fj], 0, 0, 0);
      }
    }
  }

  // C/D layout (verified m89): value r of frag (fi,fj) sits at
  // row = row0 + fi*16 + lg*4 + r, col = col0 + fj*16 + ln.
  float si[2][4]; int labR[2][4];
#pragma unroll
  for (int fi = 0; fi < 2; ++fi)
#pragma unroll
    for (int r = 0; r < 4; ++r) {
      const int row = row0 + fi * 16 + lg * 4 + r;
      si[fi][r] = sq[row];
      labR[fi][r] = labels[row];
    }

  float dacc[2][4] = {}, pacc[2][4] = {}, nacc[2][4] = {};
#pragma unroll
  for (int fj = 0; fj < 8; ++fj) {
    const int col = col0 + fj * 16 + ln;
    const float sjv = sq[col];
    const int   ljv = labels[col];
    const float qv = C_CONST * sjv;
    const float b  = 1.f - qv;
    const float b2 = b * b;
#pragma unroll
    for (int fi = 0; fi < 2; ++fi)
#pragma unroll
      for (int r = 0; r < 4; ++r) {
        const int row = row0 + fi * 16 + lg * 4 + r;
        const float g  = acc[fi][fj][r];
        const float pi_ = C_CONST * si[fi][r];
        const float tt = fmaf(-2.f * C_CONST, g, 1.f);     // 1 - 2Cg
        const float a  = tt + pi_;                         // 1 - 2Cg + C si
        const float den = fabsf(fmaf(pi_, qv, tt));        // |1 - 2Cg + C^2 si sj|
        float ns = a * a * sjv;
        ns = fmaf(b2, si[fi][r], ns);
        ns = fmaf(-2.f * a * b, g, ns);
        ns = fmaxf(ns, 0.f);
        const float rr = __builtin_amdgcn_sqrtf(C_CONST * ns);
        float ratio = (den - rr) * __builtin_amdgcn_rcpf(den + rr);
        ratio = fmaxf(ratio, RATIO_MIN);
        const float P = __builtin_amdgcn_logf(ratio);      // log2(ratio)
        const float e = __builtin_amdgcn_exp2f(20.f * P);  // exp(logit)
        const bool diag = (col == row);
        const bool same = (ljv == labR[fi][r]) && !diag;
        dacc[fi][r] += diag ? 0.f : e;
        pacc[fi][r] += same ? LOGIT_SCALE * P : 0.f;
        nacc[fi][r] += same ? 1.f : 0.f;
      }
  }

  // reduce over the 16 ln lanes, then one atomic per row per stat
#pragma unroll
  for (int fi = 0; fi < 2; ++fi)
#pragma unroll
    for (int r = 0; r < 4; ++r) {
      float d = dacc[fi][r], p = pacc[fi][r], n = nacc[fi][r];
#pragma unroll
      for (int off = 1; off < 16; off <<= 1) {
        d += __shfl_xor(d, off);
        p += __shfl_xor(p, off);
        n += __shfl_xor(n, off);
      }
      if (ln == 0) {
        const int row = row0 + fi * 16 + lg * 4 + r;
        atomicAdd(&denom[row], d);
        atomicAdd(&possum[row], p);
        atomicAdd(&npos[row], n);
      }
    }
}

__global__ void finalize_kernel(const float* __restrict__ denom,
                                const float* __restrict__ possum,
                                const float* __restrict__ npos,
                                float* __restrict__ out, int B) {
  float s_loss = 0.f, s_valid = 0.f;
  for (int i = threadIdx.x; i < B; i += 256) {
    float np = npos[i];
    if (np > 0.f) {
      float rl = -(possum[i] - np * logf(denom[i])) / np * TEMP;
      if (!(rl != rl)) s_loss += rl;   // NaN -> 0 like reference
      s_valid += 1.f;
    }
  }
#pragma unroll
  for (int off = 1; off < 64; off <<= 1) {
    s_loss += __shfl_xor(s_loss, off);
    s_valid += __shfl_xor(s_valid, off);
  }
  __shared__ float red[8];
  int wid = threadIdx.x >> 6;
  if ((threadIdx.x & 63) == 0) { red[wid] = s_loss; red[wid + 4] = s_valid; }
  __syncthreads();
  if (threadIdx.x == 0) {
    float L = red[0] + red[1] + red[2] + red[3];
    float V = red[4] + red[5] + red[6] + red[7];
    out[0] = L / fmaxf(V, 1.f);
  }
}

extern "C" void kernel_launch(void* const* d_in, const int* in_sizes, int n_in,
                              void* d_out, int out_size, void* d_ws, size_t ws_size,
                              hipStream_t stream) {
  const float* F = (const float*)d_in[0];
  const int* labels = (const int*)d_in[1];
  const int B = in_sizes[1];           // 4096

  float* sq     = (float*)d_ws;
  float* denom  = sq + B;
  float* possum = denom + B;
  float* npos   = possum + B;
  __bf16* Fh = (__bf16*)(npos + B);
  __bf16* Fl = Fh + (size_t)B * DD;

  prep_kernel<<<dim3(B / 8), dim3(256), 0, stream>>>(F, Fh, Fl, sq, denom, possum, npos);
  gram_kernel<<<dim3(B / 128, B / 128), dim3(256), 0, stream>>>(Fh, Fl, sq, labels,
                                                                denom, possum, npos);
  finalize_kernel<<<1, dim3(256), 0, stream>>>(denom, possum, npos, (float*)d_out, B);
}

// Round 4
// 72.854 us; speedup vs baseline: 1.3080x; 1.0188x over previous
//
#include <hip/hip_runtime.h>
#include <cstddef>

// Hyperbolic supervised contrastive loss, fused, MFMA split-bf16 Gram,
// upper-triangular tiles only (G and all per-pair stats are symmetric).
// G = F F^T with F = hi + lo (bf16 split): G ~= hi*hi^T + hi*lo^T + lo*hi^T.
// logits_max cancels (softmax shift invariance). Per-row stats additive -> atomics.
// exp(logit) = ratio^20, logit = 20*ln2*log2(ratio), ratio=(|den|-r)/(|den|+r).

typedef __bf16 bf16x8 __attribute__((ext_vector_type(8)));
typedef __bf16 bf16x4 __attribute__((ext_vector_type(4)));
typedef float  f32x4  __attribute__((ext_vector_type(4)));

#define C_CONST 0.01f
#define RATIO_MIN 5.000025e-06f           // ratio at clamp 1-1e-5
#define LOGIT_SCALE 13.86294361119890619f // 20*ln(2)
#define TEMP 0.5f
#define LN2 0.69314718055994530942f
constexpr int DD = 128;

// bf16-split + row squared-norms + zero the stat arrays. 8 rows/block, 32 lanes/row.
__global__ __launch_bounds__(256) void prep_kernel(
    const float* __restrict__ F, __bf16* __restrict__ Fh, __bf16* __restrict__ Fl,
    float* __restrict__ sq, float* __restrict__ denom,
    float* __restrict__ possum, float* __restrict__ npos) {
  const int tid = threadIdx.x;
  const int lane = tid & 31;
  const int row = blockIdx.x * 8 + (tid >> 5);
  const float4 v = *reinterpret_cast<const float4*>(F + (size_t)row * DD + lane * 4);
  float s = v.x * v.x + v.y * v.y + v.z * v.z + v.w * v.w;
  bf16x4 h, lo;
  h[0] = (__bf16)v.x; lo[0] = (__bf16)(v.x - (float)h[0]);
  h[1] = (__bf16)v.y; lo[1] = (__bf16)(v.y - (float)h[1]);
  h[2] = (__bf16)v.z; lo[2] = (__bf16)(v.z - (float)h[2]);
  h[3] = (__bf16)v.w; lo[3] = (__bf16)(v.w - (float)h[3]);
  *reinterpret_cast<bf16x4*>(Fh + (size_t)row * DD + lane * 4) = h;
  *reinterpret_cast<bf16x4*>(Fl + (size_t)row * DD + lane * 4) = lo;
#pragma unroll
  for (int off = 1; off < 32; off <<= 1) s += __shfl_xor(s, off);
  if (lane == 0) { sq[row] = s; denom[row] = 0.f; possum[row] = 0.f; npos[row] = 0.f; }
}

// One 128x128 G tile per block, upper-triangular tile (bi<=bj) only.
// 4 waves; wave w owns rows w*32..w*32+31 (2 row-frags x 8 col-frags).
// Fragments loaded straight from L2: A frags hoisted to regs, B streamed per fj.
__global__ __launch_bounds__(256, 2) void gram_kernel(
    const __bf16* __restrict__ Fh, const __bf16* __restrict__ Fl,
    const float* __restrict__ sq, const int* __restrict__ labels,
    float* __restrict__ denom, float* __restrict__ possum, float* __restrict__ npos,
    int nt) {
  __shared__ float colD[128], colP[128], colN[128];
  const int tid = threadIdx.x;
  const int l  = tid & 63;
  const int w  = tid >> 6;
  const int lg = l >> 4, ln = l & 15;

  // triangular decode: block t -> (bi, bj), bi <= bj.  S(bi) = bi*nt - bi(bi-1)/2
  const int t = blockIdx.x;
  int bi = (int)((2 * nt + 1 - sqrtf((float)((2 * nt + 1) * (2 * nt + 1) - 8 * t))) * 0.5f);
  while ((bi + 1) * nt - ((bi + 1) * bi) / 2 <= t) ++bi;
  while (bi * nt - (bi * (bi - 1)) / 2 > t) --bi;
  const int bj = bi + (t - (bi * nt - (bi * (bi - 1)) / 2));

  if (tid < 128) { colD[tid] = 0.f; colP[tid] = 0.f; colN[tid] = 0.f; }
  __syncthreads();

  const int row0 = bi * 128 + w * 32;
  const int col0 = bj * 128;

  const __bf16* Ah = Fh + (size_t)(row0 + ln) * DD + lg * 8;
  const __bf16* Al = Fl + (size_t)(row0 + ln) * DD + lg * 8;
  const __bf16* Bh = Fh + (size_t)(col0 + ln) * DD + lg * 8;
  const __bf16* Bl = Fl + (size_t)(col0 + ln) * DD + lg * 8;

  // hoist all A fragments (16 x 16B)
  bf16x8 ah[2][4], al[2][4];
#pragma unroll
  for (int fi = 0; fi < 2; ++fi)
#pragma unroll
    for (int kt = 0; kt < 4; ++kt) {
      ah[fi][kt] = *reinterpret_cast<const bf16x8*>(Ah + fi * 16 * DD + kt * 32);
      al[fi][kt] = *reinterpret_cast<const bf16x8*>(Al + fi * 16 * DD + kt * 32);
    }

  f32x4 acc[2][8];
#pragma unroll
  for (int fi = 0; fi < 2; ++fi)
#pragma unroll
    for (int fj = 0; fj < 8; ++fj) acc[fi][fj] = (f32x4){0.f, 0.f, 0.f, 0.f};

#pragma unroll
  for (int fj = 0; fj < 8; ++fj) {
    bf16x8 bh[4], bl[4];
#pragma unroll
    for (int kt = 0; kt < 4; ++kt) {
      bh[kt] = *reinterpret_cast<const bf16x8*>(Bh + fj * 16 * DD + kt * 32);
      bl[kt] = *reinterpret_cast<const bf16x8*>(Bl + fj * 16 * DD + kt * 32);
    }
#pragma unroll
    for (int kt = 0; kt < 4; ++kt)
#pragma unroll
      for (int fi = 0; fi < 2; ++fi) {
        acc[fi][fj] = __builtin_amdgcn_mfma_f32_16x16x32_bf16(ah[fi][kt], bh[kt], acc[fi][fj], 0, 0, 0);
        acc[fi][fj] = __builtin_amdgcn_mfma_f32_16x16x32_bf16(ah[fi][kt], bl[kt], acc[fi][fj], 0, 0, 0);
        acc[fi][fj] = __builtin_amdgcn_mfma_f32_16x16x32_bf16(al[fi][kt], bh[kt], acc[fi][fj], 0, 0, 0);
      }
  }

  // C/D layout (verified m89): value r of frag (fi,fj) at
  // row = row0 + fi*16 + lg*4 + r, col = col0 + fj*16 + ln.
  float si[2][4]; int li[2][4];
#pragma unroll
  for (int fi = 0; fi < 2; ++fi)
#pragma unroll
    for (int r = 0; r < 4; ++r) {
      const int row = row0 + fi * 16 + lg * 4 + r;
      si[fi][r] = sq[row];
      li[fi][r] = labels[row];
    }

  float dacc[2][4] = {}, pacc[2][4] = {}, nacc[2][4] = {};

  if (bi != bj) {
    // off-diagonal tile: each pair contributes to its row AND its col (symmetry)
#pragma unroll
    for (int fj = 0; fj < 8; ++fj) {
      const int col = col0 + fj * 16 + ln;
      const float sjv = sq[col];
      const int   ljv = labels[col];
      const float qv = C_CONST * sjv;
      const float b  = 1.f - qv;
      const float b2 = b * b;
      float cd = 0.f, cp = 0.f, cn = 0.f;
#pragma unroll
      for (int fi = 0; fi < 2; ++fi)
#pragma unroll
        for (int r = 0; r < 4; ++r) {
          const float g   = acc[fi][fj][r];
          const float pi_ = C_CONST * si[fi][r];
          const float tt  = fmaf(-2.f * C_CONST, g, 1.f);
          const float a   = tt + pi_;
          const float den = fabsf(fmaf(pi_, qv, tt));
          float ns = a * a * sjv;
          ns = fmaf(b2, si[fi][r], ns);
          ns = fmaf(-2.f * a * b, g, ns);
          ns = fmaxf(ns, 0.f);
          const float rr = __builtin_amdgcn_sqrtf(C_CONST * ns);
          float ratio = (den - rr) * __builtin_amdgcn_rcpf(den + rr);
          ratio = fmaxf(ratio, RATIO_MIN);
          const float P = __builtin_amdgcn_logf(ratio);
          const float e = __builtin_amdgcn_exp2f(20.f * P);
          const bool same = (ljv == li[fi][r]);
          const float sp = same ? LOGIT_SCALE * P : 0.f;
          const float sn = same ? 1.f : 0.f;
          dacc[fi][r] += e;  pacc[fi][r] += sp;  nacc[fi][r] += sn;
          cd += e;  cp += sp;  cn += sn;
        }
      // col-side: reduce the 4 lg groups, then cross-wave via LDS atomics
      cd += __shfl_xor(cd, 16); cd += __shfl_xor(cd, 32);
      cp += __shfl_xor(cp, 16); cp += __shfl_xor(cp, 32);
      cn += __shfl_xor(cn, 16); cn += __shfl_xor(cn, 32);
      if (l < 16) {
        atomicAdd(&colD[fj * 16 + ln], cd);
        atomicAdd(&colP[fj * 16 + ln], cp);
        atomicAdd(&colN[fj * 16 + ln], cn);
      }
    }
  } else {
    // diagonal tile: full epilogue, row stats only, exclude diag
#pragma unroll
    for (int fj = 0; fj < 8; ++fj) {
      const int col = col0 + fj * 16 + ln;
      const float sjv = sq[col];
      const int   ljv = labels[col];
      const float qv = C_CONST * sjv;
      const float b  = 1.f - qv;
      const float b2 = b * b;
#pragma unroll
      for (int fi = 0; fi < 2; ++fi)
#pragma unroll
        for (int r = 0; r < 4; ++r) {
          const int row = row0 + fi * 16 + lg * 4 + r;
          const float g   = acc[fi][fj][r];
          const float pi_ = C_CONST * si[fi][r];
          const float tt  = fmaf(-2.f * C_CONST, g, 1.f);
          const float a   = tt + pi_;
          const float den = fabsf(fmaf(pi_, qv, tt));
          float ns = a * a * sjv;
          ns = fmaf(b2, si[fi][r], ns);
          ns = fmaf(-2.f * a * b, g, ns);
          ns = fmaxf(ns, 0.f);
          const float rr = __builtin_amdgcn_sqrtf(C_CONST * ns);
          float ratio = (den - rr) * __builtin_amdgcn_rcpf(den + rr);
          ratio = fmaxf(ratio, RATIO_MIN);
          const float P = __builtin_amdgcn_logf(ratio);
          const float e = __builtin_amdgcn_exp2f(20.f * P);
          const bool diag = (col == row);
          const bool same = (ljv == li[fi][r]) && !diag;
          dacc[fi][r] += diag ? 0.f : e;
          pacc[fi][r] += same ? LOGIT_SCALE * P : 0.f;
          nacc[fi][r] += same ? 1.f : 0.f;
        }
    }
  }

  // row-side: reduce over the 16 ln lanes, one atomic per row per stat
#pragma unroll
  for (int fi = 0; fi < 2; ++fi)
#pragma unroll
    for (int r = 0; r < 4; ++r) {
      float d = dacc[fi][r], p = pacc[fi][r], n = nacc[fi][r];
#pragma unroll
      for (int off = 1; off < 16; off <<= 1) {
        d += __shfl_xor(d, off);
        p += __shfl_xor(p, off);
        n += __shfl_xor(n, off);
      }
      if (ln == 0) {
        const int row = row0 + fi * 16 + lg * 4 + r;
        atomicAdd(&denom[row], d);
        atomicAdd(&possum[row], p);
        atomicAdd(&npos[row], n);
      }
    }

  if (bi != bj) {
    __syncthreads();
    if (tid < 128) {
      atomicAdd(&denom[col0 + tid], colD[tid]);
      atomicAdd(&possum[col0 + tid], colP[tid]);
      atomicAdd(&npos[col0 + tid], colN[tid]);
    }
  }
}

__global__ void finalize_kernel(const float* __restrict__ denom,
                                const float* __restrict__ possum,
                                const float* __restrict__ npos,
                                float* __restrict__ out, int B) {
  float s_loss = 0.f, s_valid = 0.f;
  for (int i = threadIdx.x; i < B; i += 256) {
    float np = npos[i];
    if (np > 0.f) {
      float ln_d = __builtin_amdgcn_logf(denom[i]) * LN2;
      float rl = -(possum[i] - np * ln_d) / np * TEMP;
      if (!(rl != rl)) s_loss += rl;   // NaN -> 0 like reference
      s_valid += 1.f;
    }
  }
#pragma unroll
  for (int off = 1; off < 64; off <<= 1) {
    s_loss += __shfl_xor(s_loss, off);
    s_valid += __shfl_xor(s_valid, off);
  }
  __shared__ float red[8];
  int wid = threadIdx.x >> 6;
  if ((threadIdx.x & 63) == 0) { red[wid] = s_loss; red[wid + 4] = s_valid; }
  __syncthreads();
  if (threadIdx.x == 0) {
    float L = red[0] + red[1] + red[2] + red[3];
    float V = red[4] + red[5] + red[6] + red[7];
    out[0] = L / fmaxf(V, 1.f);
  }
}

extern "C" void kernel_launch(void* const* d_in, const int* in_sizes, int n_in,
                              void* d_out, int out_size, void* d_ws, size_t ws_size,
                              hipStream_t stream) {
  const float* F = (const float*)d_in[0];
  const int* labels = (const int*)d_in[1];
  const int B = in_sizes[1];           // 4096

  float* sq     = (float*)d_ws;
  float* denom  = sq + B;
  float* possum = denom + B;
  float* npos   = possum + B;
  __bf16* Fh = (__bf16*)(npos + B);
  __bf16* Fl = Fh + (size_t)B * DD;

  const int nt = B / 128;
  const int ntri = nt * (nt + 1) / 2;

  prep_kernel<<<dim3(B / 8), dim3(256), 0, stream>>>(F, Fh, Fl, sq, denom, possum, npos);
  gram_kernel<<<dim3(ntri), dim3(256), 0, stream>>>(Fh, Fl, sq, labels,
                                                    denom, possum, npos, nt);
  finalize_kernel<<<1, dim3(256), 0, stream>>>(denom, possum, npos, (float*)d_out, B);
}

// Round 5
// 70.840 us; speedup vs baseline: 1.3451x; 1.0284x over previous
//
#include <hip/hip_runtime.h>
#include <cstddef>

// Hyperbolic supervised contrastive loss, fused, MFMA split-bf16 Gram.
// G = F F^T with F = hi + lo (bf16 split): G ~= hi*hi^T + hi*lo^T + lo*hi^T.
// logits_max cancels (softmax shift invariance).
// Row-stationary: block (bi,s) does rows bi*128..+127 vs col tiles s*2, s*2+1;
// row stats live in registers, written as per-split partials (NO global atomics
// -- rounds 3/4 were bound by ~400K contended device-scope atomicAdds).
// exp(logit) = ratio^20, logit = 20*ln2*log2(ratio), ratio=(|den|-r)/(|den|+r).

typedef __bf16 bf16x8 __attribute__((ext_vector_type(8)));
typedef __bf16 bf16x4 __attribute__((ext_vector_type(4)));
typedef float  f32x4  __attribute__((ext_vector_type(4)));

#define C_CONST 0.01f
#define RATIO_MIN 5.000025e-06f           // ratio at clamp 1-1e-5
#define LOGIT_SCALE 13.86294361119890619f // 20*ln(2)
#define TEMP 0.5f
#define LN2 0.69314718055994530942f
constexpr int DD = 128;
constexpr int NSPLIT = 16;   // column splits; each block handles 32/NSPLIT=2 tiles
constexpr int TPS = 2;       // tiles per split

// bf16-split + row squared-norms. 8 rows/block, 32 lanes/row.
__global__ __launch_bounds__(256) void prep_kernel(
    const float* __restrict__ F, __bf16* __restrict__ Fh, __bf16* __restrict__ Fl,
    float* __restrict__ sq) {
  const int tid = threadIdx.x;
  const int lane = tid & 31;
  const int row = blockIdx.x * 8 + (tid >> 5);
  const float4 v = *reinterpret_cast<const float4*>(F + (size_t)row * DD + lane * 4);
  float s = v.x * v.x + v.y * v.y + v.z * v.z + v.w * v.w;
  bf16x4 h, lo;
  h[0] = (__bf16)v.x; lo[0] = (__bf16)(v.x - (float)h[0]);
  h[1] = (__bf16)v.y; lo[1] = (__bf16)(v.y - (float)h[1]);
  h[2] = (__bf16)v.z; lo[2] = (__bf16)(v.z - (float)h[2]);
  h[3] = (__bf16)v.w; lo[3] = (__bf16)(v.w - (float)h[3]);
  *reinterpret_cast<bf16x4*>(Fh + (size_t)row * DD + lane * 4) = h;
  *reinterpret_cast<bf16x4*>(Fl + (size_t)row * DD + lane * 4) = lo;
#pragma unroll
  for (int off = 1; off < 32; off <<= 1) s += __shfl_xor(s, off);
  if (lane == 0) sq[row] = s;
}

// 4 waves; wave w owns rows row0..row0+31 (2 row-frags). A frags hoisted to regs,
// B frags streamed from L2 per fj. C/D layout (verified m89): value r of frag
// (fi,fj) at row = row0 + fi*16 + lg*4 + r, col = col0 + fj*16 + ln.
__global__ __launch_bounds__(256, 2) void gram_kernel(
    const __bf16* __restrict__ Fh, const __bf16* __restrict__ Fl,
    const float* __restrict__ sq, const int* __restrict__ labels,
    float* __restrict__ dpart, float* __restrict__ ppart, float* __restrict__ npart,
    int B) {
  const int tid = threadIdx.x;
  const int l  = tid & 63;
  const int w  = tid >> 6;
  const int lg = l >> 4, ln = l & 15;
  const int row0 = blockIdx.x * 128 + w * 32;
  const int s = blockIdx.y;

  const __bf16* Ah = Fh + (size_t)(row0 + ln) * DD + lg * 8;
  const __bf16* Al = Fl + (size_t)(row0 + ln) * DD + lg * 8;

  // hoist all A fragments (16 x 16B = 64 VGPR)
  bf16x8 ah[2][4], al[2][4];
#pragma unroll
  for (int fi = 0; fi < 2; ++fi)
#pragma unroll
    for (int kt = 0; kt < 4; ++kt) {
      ah[fi][kt] = *reinterpret_cast<const bf16x8*>(Ah + fi * 16 * DD + kt * 32);
      al[fi][kt] = *reinterpret_cast<const bf16x8*>(Al + fi * 16 * DD + kt * 32);
    }

  float si[2][4]; int li[2][4];
#pragma unroll
  for (int fi = 0; fi < 2; ++fi)
#pragma unroll
    for (int r = 0; r < 4; ++r) {
      const int row = row0 + fi * 16 + lg * 4 + r;
      si[fi][r] = sq[row];
      li[fi][r] = labels[row];
    }

  float dacc[2][4] = {}, pacc[2][4] = {}, nacc[2][4] = {};

#pragma unroll
  for (int t2 = 0; t2 < TPS; ++t2) {
    const int col0 = (s * TPS + t2) * 128;
    const __bf16* Bh = Fh + (size_t)(col0 + ln) * DD + lg * 8;
    const __bf16* Bl = Fl + (size_t)(col0 + ln) * DD + lg * 8;

    f32x4 acc[2][8];
#pragma unroll
    for (int fi = 0; fi < 2; ++fi)
#pragma unroll
      for (int fj = 0; fj < 8; ++fj) acc[fi][fj] = (f32x4){0.f, 0.f, 0.f, 0.f};

#pragma unroll
    for (int fj = 0; fj < 8; ++fj) {
      bf16x8 bh[4], bl[4];
#pragma unroll
      for (int kt = 0; kt < 4; ++kt) {
        bh[kt] = *reinterpret_cast<const bf16x8*>(Bh + fj * 16 * DD + kt * 32);
        bl[kt] = *reinterpret_cast<const bf16x8*>(Bl + fj * 16 * DD + kt * 32);
      }
#pragma unroll
      for (int kt = 0; kt < 4; ++kt)
#pragma unroll
        for (int fi = 0; fi < 2; ++fi) {
          acc[fi][fj] = __builtin_amdgcn_mfma_f32_16x16x32_bf16(ah[fi][kt], bh[kt], acc[fi][fj], 0, 0, 0);
          acc[fi][fj] = __builtin_amdgcn_mfma_f32_16x16x32_bf16(ah[fi][kt], bl[kt], acc[fi][fj], 0, 0, 0);
          acc[fi][fj] = __builtin_amdgcn_mfma_f32_16x16x32_bf16(al[fi][kt], bh[kt], acc[fi][fj], 0, 0, 0);
        }
    }

    // epilogue: per-pair transform, accumulate row stats in registers
#pragma unroll
    for (int fj = 0; fj < 8; ++fj) {
      const int col = col0 + fj * 16 + ln;
      const float sjv = sq[col];
      const int   ljv = labels[col];
      const float qv = C_CONST * sjv;
      const float b  = 1.f - qv;
      const float b2 = b * b;
#pragma unroll
      for (int fi = 0; fi < 2; ++fi)
#pragma unroll
        for (int r = 0; r < 4; ++r) {
          const int row = row0 + fi * 16 + lg * 4 + r;
          const float g   = acc[fi][fj][r];
          const float pi_ = C_CONST * si[fi][r];
          const float tt  = fmaf(-2.f * C_CONST, g, 1.f);   // 1 - 2Cg
          const float a   = tt + pi_;                       // 1 - 2Cg + C si
          const float den = fabsf(fmaf(pi_, qv, tt));       // |1-2Cg+C^2 si sj|
          float ns = a * a * sjv;
          ns = fmaf(b2, si[fi][r], ns);
          ns = fmaf(-2.f * a * b, g, ns);
          ns = fmaxf(ns, 0.f);
          const float rr = __builtin_amdgcn_sqrtf(C_CONST * ns);
          float ratio = (den - rr) * __builtin_amdgcn_rcpf(den + rr);
          ratio = fmaxf(ratio, RATIO_MIN);
          const float P = __builtin_amdgcn_logf(ratio);     // log2(ratio)
          const float e = __builtin_amdgcn_exp2f(20.f * P); // exp(logit)
          const bool diag = (col == row);
          const bool same = (ljv == li[fi][r]) && !diag;
          dacc[fi][r] += diag ? 0.f : e;
          pacc[fi][r] += same ? LOGIT_SCALE * P : 0.f;
          nacc[fi][r] += same ? 1.f : 0.f;
        }
    }
  }

  // reduce over the 16 ln lanes; plain partial stores (no atomics)
#pragma unroll
  for (int fi = 0; fi < 2; ++fi)
#pragma unroll
    for (int r = 0; r < 4; ++r) {
      float d = dacc[fi][r], p = pacc[fi][r], n = nacc[fi][r];
#pragma unroll
      for (int off = 1; off < 16; off <<= 1) {
        d += __shfl_xor(d, off);
        p += __shfl_xor(p, off);
        n += __shfl_xor(n, off);
      }
      if (ln == 0) {
        const size_t idx = (size_t)s * B + (row0 + fi * 16 + lg * 4 + r);
        dpart[idx] = d;
        ppart[idx] = p;
        npart[idx] = n;
      }
    }
}

__global__ __launch_bounds__(1024) void finalize_kernel(
    const float* __restrict__ dpart, const float* __restrict__ ppart,
    const float* __restrict__ npart, float* __restrict__ out, int B) {
  float s_loss = 0.f, s_valid = 0.f;
  for (int i = threadIdx.x; i < B; i += 1024) {
    float d = 0.f, p = 0.f, n = 0.f;
#pragma unroll
    for (int s = 0; s < NSPLIT; ++s) {
      d += dpart[(size_t)s * B + i];     // coalesced across threads
      p += ppart[(size_t)s * B + i];
      n += npart[(size_t)s * B + i];
    }
    if (n > 0.f) {
      float ln_d = __builtin_amdgcn_logf(d) * LN2;
      float rl = -(p - n * ln_d) / n * TEMP;
      if (!(rl != rl)) s_loss += rl;     // NaN -> 0 like reference
      s_valid += 1.f;
    }
  }
#pragma unroll
  for (int off = 1; off < 64; off <<= 1) {
    s_loss += __shfl_xor(s_loss, off);
    s_valid += __shfl_xor(s_valid, off);
  }
  __shared__ float red[32];
  const int wid = threadIdx.x >> 6;
  if ((threadIdx.x & 63) == 0) { red[wid] = s_loss; red[wid + 16] = s_valid; }
  __syncthreads();
  if (threadIdx.x == 0) {
    float L = 0.f, V = 0.f;
#pragma unroll
    for (int i = 0; i < 16; ++i) { L += red[i]; V += red[i + 16]; }
    out[0] = L / fmaxf(V, 1.f);
  }
}

extern "C" void kernel_launch(void* const* d_in, const int* in_sizes, int n_in,
                              void* d_out, int out_size, void* d_ws, size_t ws_size,
                              hipStream_t stream) {
  const float* F = (const float*)d_in[0];
  const int* labels = (const int*)d_in[1];
  const int B = in_sizes[1];           // 4096

  float* sq    = (float*)d_ws;
  float* dpart = sq + B;
  float* ppart = dpart + (size_t)NSPLIT * B;
  float* npart = ppart + (size_t)NSPLIT * B;
  __bf16* Fh = (__bf16*)(npart + (size_t)NSPLIT * B);
  __bf16* Fl = Fh + (size_t)B * DD;

  prep_kernel<<<dim3(B / 8), dim3(256), 0, stream>>>(F, Fh, Fl, sq);
  gram_kernel<<<dim3(B / 128, NSPLIT), dim3(256), 0, stream>>>(
      Fh, Fl, sq, labels, dpart, ppart, npart, B);
  finalize_kernel<<<1, dim3(1024), 0, stream>>>(dpart, ppart, npart, (float*)d_out, B);
}